// Round 3
// baseline (176.134 us; speedup 1.0000x reference)
//
#include <hip/hip_runtime.h>
#include <hip/hip_bf16.h>
#include <math.h>

#define TOKENS 8192
#define D_REAL 768
#define D_HID  512
#define D_MODEL 4096

typedef __attribute__((ext_vector_type(8))) short bf16x8;   // 8 bf16 in 4 VGPRs
typedef __attribute__((ext_vector_type(4))) float f32x4;    // MFMA accumulator

// fp32 -> bf16, round-to-nearest-even
__device__ inline unsigned short f2bf(float f) {
    union { float f; unsigned u; } v; v.f = f;
    unsigned r = v.u + 0x7FFFu + ((v.u >> 16) & 1u);
    return (unsigned short)(r >> 16);
}
__device__ inline unsigned pack2(float lo, float hi) {
    return (unsigned)f2bf(lo) | ((unsigned)f2bf(hi) << 16);
}
__device__ inline bf16x8 cvt8(float4 a, float4 b) {
    bf16x8 r;
    r[0] = (short)f2bf(a.x); r[1] = (short)f2bf(a.y);
    r[2] = (short)f2bf(a.z); r[3] = (short)f2bf(a.w);
    r[4] = (short)f2bf(b.x); r[5] = (short)f2bf(b.y);
    r[6] = (short)f2bf(b.z); r[7] = (short)f2bf(b.w);
    return r;
}

// async global->LDS, 16B per lane. LDS dest = wave-uniform base + lane*16.
__device__ inline void gload_lds16(const void* g, void* lds_wave_base) {
    __builtin_amdgcn_global_load_lds(
        (const __attribute__((address_space(1))) unsigned*)g,
        (__attribute__((address_space(3))) unsigned*)lds_wave_base,
        16, 0, 0);
}

// ---------------------------------------------------------------------------
// Fused GEMM1 + LayerNorm + ELU:
//   H[t] = elu(ln(real[ids[t]] @ w1^T))   M=8192, N=512 (full), K=768
// Tile BM=64 x BN=512, BK=32. 1024 threads = 16 waves (2 row x 8 col),
// each wave 32x64 = 2x4 fragments of 16x16x32. A,B staged fp32->bf16 in regs.
// LN needs full rows -> done in epilogue via shfl + LDS cross-wave reduce.
// ---------------------------------------------------------------------------
__global__ __launch_bounds__(1024)
void gemm1_ln(const float* __restrict__ real, const float* __restrict__ w1,
              const int* __restrict__ ids,
              const float* __restrict__ ln_w, const float* __restrict__ ln_b,
              unsigned short* __restrict__ H)
{
    __shared__ __align__(16) unsigned short As[64 * 32];
    __shared__ __align__(16) unsigned short Bs[512 * 32];
    __shared__ float redS[64][8];
    __shared__ float redQ[64][8];
    __shared__ int sIds[64];

    const int tid = threadIdx.x;
    const int rowBase = blockIdx.x * 64;
    if (tid < 64) sIds[tid] = ids[rowBase + tid];
    __syncthreads();

    // staging: A = 64 rows x 32 k fp32 (2 fp32/thread), B = 512 rows x 32 k (16 fp32/thread)
    const int ar = tid >> 4;           // 0..63
    const int ac = (tid & 15) * 2;     // k offset within BK
    const int br = tid >> 1;           // 0..511
    const int bh = (tid & 1) * 16;     // k half within BK

    const float* gA = real + (size_t)sIds[ar] * D_REAL + ac;
    const float* gB = w1 + (size_t)br * D_REAL + bh;

    const int lane = tid & 63;
    const int wv = tid >> 6;           // 0..15
    const int wr = wv >> 3;            // 0..1  (row half)
    const int wc = wv & 7;             // 0..7  (col chunk)
    const int frow = lane & 15;
    const int fk = (lane >> 4) * 8;

    f32x4 acc[2][4];
    #pragma unroll
    for (int i = 0; i < 2; i++)
        #pragma unroll
        for (int j = 0; j < 4; j++) acc[i][j] = (f32x4)0.f;

    for (int k0 = 0; k0 < D_REAL; k0 += 32) {
        const float2 av = *reinterpret_cast<const float2*>(gA + k0);
        const float4 b0 = *reinterpret_cast<const float4*>(gB + k0);
        const float4 b1 = *reinterpret_cast<const float4*>(gB + k0 + 4);
        const float4 b2 = *reinterpret_cast<const float4*>(gB + k0 + 8);
        const float4 b3 = *reinterpret_cast<const float4*>(gB + k0 + 12);
        __syncthreads();   // previous iter's frag reads done before overwrite
        reinterpret_cast<unsigned*>(As)[ar * 16 + (ac >> 1)] = pack2(av.x, av.y);
        *reinterpret_cast<bf16x8*>(&Bs[br * 32 + bh])     = cvt8(b0, b1);
        *reinterpret_cast<bf16x8*>(&Bs[br * 32 + bh + 8]) = cvt8(b2, b3);
        __syncthreads();

        bf16x8 af[2], bg[4];
        #pragma unroll
        for (int i = 0; i < 2; i++)
            af[i] = *reinterpret_cast<const bf16x8*>(&As[(wr*32 + i*16 + frow) * 32 + fk]);
        #pragma unroll
        for (int j = 0; j < 4; j++)
            bg[j] = *reinterpret_cast<const bf16x8*>(&Bs[(wc*64 + j*16 + frow) * 32 + fk]);
        #pragma unroll
        for (int i = 0; i < 2; i++)
            #pragma unroll
            for (int j = 0; j < 4; j++)
                acc[i][j] = __builtin_amdgcn_mfma_f32_16x16x32_bf16(af[i], bg[j], acc[i][j], 0, 0, 0);
    }
    __syncthreads();

    // ---- LayerNorm + ELU epilogue ----
    // C/D frag: row = wr*32 + i*16 + (lane>>4)*4 + r, col = wc*64 + j*16 + frow.
    // Step 1: per-(i,r) partial sum over this thread's 4 cols, reduce across
    // the 16 frow lanes (masks <16 keep the lane>>4 group), write [row][wc].
    #pragma unroll
    for (int i = 0; i < 2; i++) {
        #pragma unroll
        for (int r = 0; r < 4; r++) {
            float s = 0.f, q = 0.f;
            #pragma unroll
            for (int j = 0; j < 4; j++) {
                const float v = acc[i][j][r];
                s += v; q += v * v;
            }
            #pragma unroll
            for (int m = 1; m < 16; m <<= 1) {
                s += __shfl_xor(s, m);
                q += __shfl_xor(q, m);
            }
            if (frow == 0) {
                const int row = wr*32 + i*16 + (lane >> 4)*4 + r;
                redS[row][wc] = s;
                redQ[row][wc] = q;
            }
        }
    }
    __syncthreads();

    // Step 2: finish stats, apply LN+ELU, write bf16 H.
    float wcol[4], bcol[4];
    #pragma unroll
    for (int j = 0; j < 4; j++) {
        const int col = wc*64 + j*16 + frow;
        wcol[j] = ln_w[col];
        bcol[j] = ln_b[col];
    }
    #pragma unroll
    for (int i = 0; i < 2; i++) {
        #pragma unroll
        for (int r = 0; r < 4; r++) {
            const int row = wr*32 + i*16 + (lane >> 4)*4 + r;
            float sum = 0.f, sq = 0.f;
            #pragma unroll
            for (int w = 0; w < 8; w++) { sum += redS[row][w]; sq += redQ[row][w]; }
            const float mu = sum * (1.f / D_HID);
            const float var = sq * (1.f / D_HID) - mu * mu;
            const float rstd = rsqrtf(var + 1e-5f);
            unsigned short* dst = H + (size_t)(rowBase + row) * D_HID + wc*64 + frow;
            #pragma unroll
            for (int j = 0; j < 4; j++) {
                float y = (acc[i][j][r] - mu) * rstd * wcol[j] + bcol[j];
                y = y > 0.f ? y : expm1f(y);
                dst[j * 16] = f2bf(y);
            }
        }
    }
}

// ---------------------------------------------------------------------------
// GEMM2 (m97 structure, unchanged from round 2): out = H @ w2^T + embed[ids]
// M=8192, N=4096, K=512. 128x128 tile, BK=32, 4 waves (2x2), 4x4 frags.
// ---------------------------------------------------------------------------
__global__ __launch_bounds__(256)
void gemm2_mfma(const unsigned short* __restrict__ A,
                const unsigned short* __restrict__ B,
                const int* __restrict__ ids,
                const float* __restrict__ embed,
                float* __restrict__ C)
{
    constexpr int K = D_HID, N = D_MODEL;
    __shared__ __align__(16) unsigned short As[128 * 32];
    __shared__ __align__(16) unsigned short Bs[128 * 32];
    __shared__ int sIds[128];

    const int tid = threadIdx.x;
    const int rowBase = blockIdx.x * 128;
    const int colBase = blockIdx.y * 128;

    if (tid < 128) sIds[tid] = ids[rowBase + tid];

    const int srow = tid >> 2;
    const int scol = (tid & 3) * 8;
    const unsigned short* gA = A + (size_t)(rowBase + srow) * K + scol;
    const unsigned short* gB = B + (size_t)(colBase + srow) * K + scol;
    unsigned short* lA = As + (tid >> 6) * 512;
    unsigned short* lB = Bs + (tid >> 6) * 512;

    const int lane = tid & 63;
    const int wv   = tid >> 6;
    const int wm   = (wv >> 1) * 64;
    const int wn   = (wv & 1) * 64;
    const int frow = lane & 15;
    const int fk   = (lane >> 4) * 8;

    f32x4 acc[4][4];
    #pragma unroll
    for (int i = 0; i < 4; i++)
        #pragma unroll
        for (int j = 0; j < 4; j++) acc[i][j] = (f32x4)0.f;

    for (int k0 = 0; k0 < K; k0 += 32) {
        gload_lds16(gA,                lA);
        gload_lds16(gA + (size_t)64*K, lA + 2048);
        gload_lds16(gB,                lB);
        gload_lds16(gB + (size_t)64*K, lB + 2048);
        gA += 32; gB += 32;
        __syncthreads();

        bf16x8 af[4], bg[4];
        #pragma unroll
        for (int i = 0; i < 4; i++)
            af[i] = *reinterpret_cast<const bf16x8*>(&As[(wm + i*16 + frow) * 32 + fk]);
        #pragma unroll
        for (int j = 0; j < 4; j++)
            bg[j] = *reinterpret_cast<const bf16x8*>(&Bs[(wn + j*16 + frow) * 32 + fk]);

        #pragma unroll
        for (int i = 0; i < 4; i++)
            #pragma unroll
            for (int j = 0; j < 4; j++)
                acc[i][j] = __builtin_amdgcn_mfma_f32_16x16x32_bf16(af[i], bg[j], acc[i][j], 0, 0, 0);
        __syncthreads();
    }

    const int orow0 = wm + (lane >> 4) * 4;
    const int ocol0 = wn + frow;
    #pragma unroll
    for (int i = 0; i < 4; i++) {
        #pragma unroll
        for (int r = 0; r < 4; r++) {
            const int lrow = orow0 + i * 16 + r;
            const size_t grow = (size_t)(rowBase + lrow);
            const float* e = embed + (size_t)sIds[lrow] * N + colBase + ocol0;
            #pragma unroll
            for (int j = 0; j < 4; j++)
                C[grow * N + colBase + ocol0 + j * 16] = acc[i][j][r] + e[j * 16];
        }
    }
}

// ---------------------------------------------------------------------------
// fp32 -> bf16 bulk convert (w2 only)
// ---------------------------------------------------------------------------
__global__ __launch_bounds__(256)
void convert_bf16(const float* __restrict__ src, unsigned short* __restrict__ dst, int n4)
{
    const int i = blockIdx.x * 256 + threadIdx.x;
    if (i >= n4) return;
    const float4 v = reinterpret_cast<const float4*>(src)[i];
    ushort4 o;
    o.x = f2bf(v.x); o.y = f2bf(v.y); o.z = f2bf(v.z); o.w = f2bf(v.w);
    reinterpret_cast<ushort4*>(dst)[i] = o;
}

extern "C" void kernel_launch(void* const* d_in, const int* in_sizes, int n_in,
                              void* d_out, int out_size, void* d_ws, size_t ws_size,
                              hipStream_t stream)
{
    const float* real  = (const float*)d_in[0];   // [32000, 768]
    const float* embed = (const float*)d_in[1];   // [32000, 4096]
    const float* w1    = (const float*)d_in[2];   // [512, 768]
    const float* w2    = (const float*)d_in[3];   // [4096, 512]
    const float* ln_w  = (const float*)d_in[4];   // [512]
    const float* ln_b  = (const float*)d_in[5];   // [512]
    const int*   ids   = (const int*)d_in[6];     // [8192]
    float* out = (float*)d_out;                   // [8192, 4096] fp32

    unsigned short* Hb  = (unsigned short*)d_ws;            // [8192][512] bf16 (8 MB)
    unsigned short* w2b = Hb + (size_t)TOKENS * D_HID;      // [4096][512] bf16 (4 MB)

    convert_bf16<<<(D_MODEL * D_HID / 4 + 255) / 256, 256, 0, stream>>>(w2, w2b, D_MODEL * D_HID / 4);

    // fused gather + GEMM1 + LayerNorm + ELU
    gemm1_ln<<<TOKENS / 64, 1024, 0, stream>>>(real, w1, ids, ln_w, ln_b, Hb);

    // GEMM2 + embed gather-add
    dim3 g2(TOKENS / 128, D_MODEL / 128);
    gemm2_mfma<<<g2, 256, 0, stream>>>(Hb, w2b, ids, embed, out);
}

// Round 5
// 146.615 us; speedup vs baseline: 1.2013x; 1.2013x over previous
//
#include <hip/hip_runtime.h>
#include <hip/hip_bf16.h>
#include <math.h>

#define TOKENS 8192
#define D_REAL 768
#define D_HID  512
#define D_MODEL 4096

typedef __attribute__((ext_vector_type(8))) short bf16x8;   // 8 bf16 in 4 VGPRs
typedef __attribute__((ext_vector_type(4))) float f32x4;    // MFMA accumulator

// fp32 -> bf16, round-to-nearest-even
__device__ inline unsigned short f2bf(float f) {
    union { float f; unsigned u; } v; v.f = f;
    unsigned r = v.u + 0x7FFFu + ((v.u >> 16) & 1u);
    return (unsigned short)(r >> 16);
}
__device__ inline float bf2f(unsigned short h) {
    union { unsigned u; float f; } v; v.u = ((unsigned)h) << 16;
    return v.f;
}

// async global->LDS, 16B per lane. LDS dest = wave-uniform base + lane*16.
__device__ inline void gload_lds16(const void* g, void* lds_wave_base) {
    __builtin_amdgcn_global_load_lds(
        (const __attribute__((address_space(1))) unsigned*)g,
        (__attribute__((address_space(3))) unsigned*)lds_wave_base,
        16, 0, 0);
}

// ---------------------------------------------------------------------------
// GEMM1: Hb[M=8192][N=512] = Ag[M][K=768] * w1b[N][K]^T, bf16 out.
// Tile 64x128, BK=32, 256 threads = 4 waves (2 row x 2 col), each wave
// 32x64 = 2x4 fragments of 16x16x32. Grid (128, 4) = 512 blocks (2/CU).
// ---------------------------------------------------------------------------
__global__ __launch_bounds__(256)
void gemm1_mfma(const unsigned short* __restrict__ A,
                const unsigned short* __restrict__ B,
                unsigned short* __restrict__ C)
{
    constexpr int K = D_REAL, N = D_HID;
    __shared__ __align__(16) unsigned short As[64 * 32];    // 4 KB
    __shared__ __align__(16) unsigned short Bs[128 * 32];   // 8 KB

    const int tid = threadIdx.x;
    const int rowBase = blockIdx.x * 64;
    const int colBase = blockIdx.y * 128;

    const int srow = tid >> 2;
    const int scol = (tid & 3) * 8;
    const unsigned short* gA = A + (size_t)(rowBase + srow) * K + scol;
    const unsigned short* gB = B + (size_t)(colBase + srow) * K + scol;
    // wave w stages A rows 16w..16w+15 = 1024 B -> base = w*512 shorts
    unsigned short* lA = As + (tid >> 6) * 512;
    unsigned short* lB = Bs + (tid >> 6) * 512;

    const int lane = tid & 63;
    const int wv   = tid >> 6;
    const int wm   = (wv >> 1) * 32;
    const int wn   = (wv & 1) * 64;
    const int frow = lane & 15;
    const int fk   = (lane >> 4) * 8;

    f32x4 acc[2][4];
    #pragma unroll
    for (int i = 0; i < 2; i++)
        #pragma unroll
        for (int j = 0; j < 4; j++) acc[i][j] = (f32x4)0.f;

    for (int k0 = 0; k0 < K; k0 += 32) {
        gload_lds16(gA,                lA);
        gload_lds16(gB,                lB);
        gload_lds16(gB + (size_t)64*K, lB + 2048);
        gA += 32; gB += 32;
        __syncthreads();

        bf16x8 af[2], bg[4];
        #pragma unroll
        for (int i = 0; i < 2; i++)
            af[i] = *reinterpret_cast<const bf16x8*>(&As[(wm + i*16 + frow) * 32 + fk]);
        #pragma unroll
        for (int j = 0; j < 4; j++)
            bg[j] = *reinterpret_cast<const bf16x8*>(&Bs[(wn + j*16 + frow) * 32 + fk]);

        #pragma unroll
        for (int i = 0; i < 2; i++)
            #pragma unroll
            for (int j = 0; j < 4; j++)
                acc[i][j] = __builtin_amdgcn_mfma_f32_16x16x32_bf16(af[i], bg[j], acc[i][j], 0, 0, 0);
        __syncthreads();
    }

    // Epilogue: bf16 scalar stores (C/D frag: row=(lane>>4)*4+r, col=lane&15)
    const int orow0 = wm + (lane >> 4) * 4;
    const int ocol0 = wn + frow;
    #pragma unroll
    for (int i = 0; i < 2; i++)
        #pragma unroll
        for (int r = 0; r < 4; r++) {
            unsigned short* dst = C + (size_t)(rowBase + orow0 + i*16 + r) * N + colBase + ocol0;
            #pragma unroll
            for (int j = 0; j < 4; j++)
                dst[j * 16] = f2bf(acc[i][j][r]);
        }
}

// ---------------------------------------------------------------------------
// GEMM2: out[M=8192][N=4096] = Hb * w2b^T + embed[ids], fp32 out.
// m97 K-loop (128x128, BK=32, 4 waves 2x2, 4x4 frags) + LDS-staged
// coalesced float4 epilogue (4 chunks of 32 rows through a [32][132] buffer
// overlaid on the staging LDS).
// ---------------------------------------------------------------------------
__global__ __launch_bounds__(256)
void gemm2_mfma(const unsigned short* __restrict__ A,
                const unsigned short* __restrict__ B,
                const int* __restrict__ ids,
                const float* __restrict__ embed,
                float* __restrict__ C)
{
    constexpr int K = D_HID, N = D_MODEL;
    __shared__ __align__(16) unsigned char smem[32 * 132 * 4];   // 16.9 KB
    unsigned short* As = (unsigned short*)smem;          // [128*32] bf16, 8 KB
    unsigned short* Bs = (unsigned short*)(smem + 8192); // [128*32] bf16, 8 KB
    float* Ct = (float*)smem;                            // [32][132] f32 epilogue
    __shared__ int sIds[128];

    const int tid = threadIdx.x;
    const int rowBase = blockIdx.x * 128;
    const int colBase = blockIdx.y * 128;

    if (tid < 128) sIds[tid] = ids[rowBase + tid];

    const int srow = tid >> 2;
    const int scol = (tid & 3) * 8;
    const unsigned short* gA = A + (size_t)(rowBase + srow) * K + scol;
    const unsigned short* gB = B + (size_t)(colBase + srow) * K + scol;
    unsigned short* lA = As + (tid >> 6) * 512;
    unsigned short* lB = Bs + (tid >> 6) * 512;

    const int lane = tid & 63;
    const int wv   = tid >> 6;
    const int wm   = (wv >> 1) * 64;
    const int wn   = (wv & 1) * 64;
    const int frow = lane & 15;
    const int fk   = (lane >> 4) * 8;

    f32x4 acc[4][4];
    #pragma unroll
    for (int i = 0; i < 4; i++)
        #pragma unroll
        for (int j = 0; j < 4; j++) acc[i][j] = (f32x4)0.f;

    for (int k0 = 0; k0 < K; k0 += 32) {
        gload_lds16(gA,                lA);
        gload_lds16(gA + (size_t)64*K, lA + 2048);
        gload_lds16(gB,                lB);
        gload_lds16(gB + (size_t)64*K, lB + 2048);
        gA += 32; gB += 32;
        __syncthreads();

        bf16x8 af[4], bg[4];
        #pragma unroll
        for (int i = 0; i < 4; i++)
            af[i] = *reinterpret_cast<const bf16x8*>(&As[(wm + i*16 + frow) * 32 + fk]);
        #pragma unroll
        for (int j = 0; j < 4; j++)
            bg[j] = *reinterpret_cast<const bf16x8*>(&Bs[(wn + j*16 + frow) * 32 + fk]);

        #pragma unroll
        for (int i = 0; i < 4; i++)
            #pragma unroll
            for (int j = 0; j < 4; j++)
                acc[i][j] = __builtin_amdgcn_mfma_f32_16x16x32_bf16(af[i], bg[j], acc[i][j], 0, 0, 0);
        __syncthreads();   // also protects Ct overlay below
    }

    // Coalesced epilogue. Chunk c holds tile rows {c*16..c*16+15} (wm=0 waves)
    // and {64+c*16..+15} (wm=64 waves) as LDS rows 0..15 / 16..31.
    const int rl_w = (wv >> 1) * 16 + (lane >> 4) * 4;   // this thread's LDS row base
    const int rl_r = tid >> 3;                            // read-side LDS row (0..31)
    const int cs   = (tid & 7) * 16;                      // read-side col (floats)
    #pragma unroll
    for (int c = 0; c < 4; c++) {
        if (c) __syncthreads();   // prior chunk's reads done before overwrite
        #pragma unroll
        for (int r = 0; r < 4; r++)
            #pragma unroll
            for (int j = 0; j < 4; j++)
                Ct[(rl_w + r) * 132 + wn + frow + j * 16] = acc[c][j][r];
        __syncthreads();
        const int gr = (rl_r & 15) + c * 16 + (rl_r >> 4) * 64;  // row in 128-tile
        const float* e = embed + (size_t)sIds[gr] * N + colBase + cs;
        float* dst = C + (size_t)(rowBase + gr) * N + colBase + cs;
        #pragma unroll
        for (int q = 0; q < 4; q++) {
            float4 v = *reinterpret_cast<const float4*>(&Ct[rl_r * 132 + cs + q * 4]);
            const float4 ev = *reinterpret_cast<const float4*>(e + q * 4);
            v.x += ev.x; v.y += ev.y; v.z += ev.z; v.w += ev.w;
            *reinterpret_cast<float4*>(dst + q * 4) = v;
        }
    }
}

// ---------------------------------------------------------------------------
// fp32 -> bf16 bulk convert
// ---------------------------------------------------------------------------
__global__ __launch_bounds__(256)
void convert_bf16(const float* __restrict__ src, unsigned short* __restrict__ dst, int n4)
{
    const int i = blockIdx.x * 256 + threadIdx.x;
    if (i >= n4) return;
    const float4 v = reinterpret_cast<const float4*>(src)[i];
    ushort4 o;
    o.x = f2bf(v.x); o.y = f2bf(v.y); o.z = f2bf(v.z); o.w = f2bf(v.w);
    reinterpret_cast<ushort4*>(dst)[i] = o;
}

// ---------------------------------------------------------------------------
// Gather rows of real[ids[t]] -> bf16 Ag[t]. One block (192 thr) per token.
// ---------------------------------------------------------------------------
__global__ __launch_bounds__(192)
void gather_bf16(const float* __restrict__ real, const int* __restrict__ ids,
                 unsigned short* __restrict__ Ag)
{
    const int row = blockIdx.x;
    const int t = threadIdx.x;
    const float4 v = *reinterpret_cast<const float4*>(real + (size_t)ids[row] * D_REAL + t * 4);
    ushort4 o;
    o.x = f2bf(v.x); o.y = f2bf(v.y); o.z = f2bf(v.z); o.w = f2bf(v.w);
    *reinterpret_cast<ushort4*>(Ag + (size_t)row * D_REAL + t * 4) = o;
}

// ---------------------------------------------------------------------------
// In-place LayerNorm + ELU on bf16 H [TOKENS][512]. One wave per row.
// ---------------------------------------------------------------------------
__global__ __launch_bounds__(256)
void ln_elu_bf16(unsigned short* __restrict__ H,
                 const float* __restrict__ ln_w, const float* __restrict__ ln_b)
{
    const int row = blockIdx.x * 4 + (threadIdx.x >> 6);
    const int t = threadIdx.x & 63;
    unsigned short* x = H + (size_t)row * D_HID + t * 8;

    bf16x8 v = *reinterpret_cast<const bf16x8*>(x);
    float f[8], s = 0.f, ss = 0.f;
    #pragma unroll
    for (int j = 0; j < 8; j++) {
        f[j] = bf2f((unsigned short)v[j]);
        s += f[j]; ss += f[j] * f[j];
    }
    #pragma unroll
    for (int off = 32; off > 0; off >>= 1) {
        s  += __shfl_down(s, off);
        ss += __shfl_down(ss, off);
    }
    s = __shfl(s, 0); ss = __shfl(ss, 0);
    const float mu = s * (1.f / D_HID);
    const float var = ss * (1.f / D_HID) - mu * mu;
    const float rstd = rsqrtf(var + 1e-5f);

    const float4 w0 = *reinterpret_cast<const float4*>(ln_w + t * 8);
    const float4 w1 = *reinterpret_cast<const float4*>(ln_w + t * 8 + 4);
    const float4 b0 = *reinterpret_cast<const float4*>(ln_b + t * 8);
    const float4 b1 = *reinterpret_cast<const float4*>(ln_b + t * 8 + 4);
    const float wa[8] = { w0.x, w0.y, w0.z, w0.w, w1.x, w1.y, w1.z, w1.w };
    const float ba[8] = { b0.x, b0.y, b0.z, b0.w, b1.x, b1.y, b1.z, b1.w };

    bf16x8 o;
    #pragma unroll
    for (int j = 0; j < 8; j++) {
        float y = (f[j] - mu) * rstd * wa[j] + ba[j];
        y = y > 0.f ? y : expm1f(y);
        o[j] = (short)f2bf(y);
    }
    *reinterpret_cast<bf16x8*>(x) = o;
}

extern "C" void kernel_launch(void* const* d_in, const int* in_sizes, int n_in,
                              void* d_out, int out_size, void* d_ws, size_t ws_size,
                              hipStream_t stream)
{
    const float* real  = (const float*)d_in[0];   // [32000, 768]
    const float* embed = (const float*)d_in[1];   // [32000, 4096]
    const float* w1    = (const float*)d_in[2];   // [512, 768]
    const float* w2    = (const float*)d_in[3];   // [4096, 512]
    const float* ln_w  = (const float*)d_in[4];   // [512]
    const float* ln_b  = (const float*)d_in[5];   // [512]
    const int*   ids   = (const int*)d_in[6];     // [8192]
    float* out = (float*)d_out;                   // [8192, 4096] fp32

    unsigned short* Hb  = (unsigned short*)d_ws;             // [8192][512] bf16 (8 MB)
    unsigned short* w1b = Hb  + (size_t)TOKENS * D_HID;      // [512][768]  bf16
    unsigned short* w2b = w1b + (size_t)D_HID * D_REAL;      // [4096][512] bf16
    // d_out doubles as scratch for gathered bf16 A — fully overwritten by GEMM2.
    unsigned short* Ag  = (unsigned short*)d_out;            // [8192][768] bf16

    convert_bf16<<<(D_HID * D_REAL / 4 + 255) / 256, 256, 0, stream>>>(w1, w1b, D_HID * D_REAL / 4);
    convert_bf16<<<(D_MODEL * D_HID / 4 + 255) / 256, 256, 0, stream>>>(w2, w2b, D_MODEL * D_HID / 4);
    gather_bf16<<<TOKENS, 192, 0, stream>>>(real, ids, Ag);

    dim3 g1(TOKENS / 64, D_HID / 128);
    gemm1_mfma<<<g1, 256, 0, stream>>>(Ag, w1b, Hb);

    ln_elu_bf16<<<TOKENS / 4, 256, 0, stream>>>(Hb, ln_w, ln_b);

    dim3 g2(TOKENS / 128, D_MODEL / 128);
    gemm2_mfma<<<g2, 256, 0, stream>>>(Hb, w2b, ids, embed, out);
}

// Round 6
// 129.024 us; speedup vs baseline: 1.3651x; 1.1363x over previous
//
#include <hip/hip_runtime.h>
#include <hip/hip_bf16.h>
#include <math.h>

#define TOKENS 8192
#define D_REAL 768
#define D_HID  512
#define D_MODEL 4096

typedef __attribute__((ext_vector_type(8))) short bf16x8;   // 8 bf16 in 4 VGPRs
typedef __attribute__((ext_vector_type(4))) float f32x4;    // MFMA accumulator

// fp32 -> bf16, round-to-nearest-even
__device__ inline unsigned short f2bf(float f) {
    union { float f; unsigned u; } v; v.f = f;
    unsigned r = v.u + 0x7FFFu + ((v.u >> 16) & 1u);
    return (unsigned short)(r >> 16);
}
__device__ inline float bf2f(unsigned short h) {
    union { unsigned u; float f; } v; v.u = ((unsigned)h) << 16;
    return v.f;
}

// async global->LDS, 16B per lane. LDS dest = wave-uniform base + lane*16.
__device__ inline void gload_lds16(const void* g, void* lds_wave_base) {
    __builtin_amdgcn_global_load_lds(
        (const __attribute__((address_space(1))) unsigned*)g,
        (__attribute__((address_space(3))) unsigned*)lds_wave_base,
        16, 0, 0);
}

// ---------------------------------------------------------------------------
// GEMM1: Hb[M=8192][N=512] = Ag[M][K=768] * w1b[N][K]^T, bf16 out.
// Tile 64x128, BK=32, 256 threads = 4 waves (2 row x 2 col), each wave
// 32x64 = 2x4 fragments of 16x16x32. Grid (128, 4) = 512 blocks (2/CU).
// ---------------------------------------------------------------------------
__global__ __launch_bounds__(256)
void gemm1_mfma(const unsigned short* __restrict__ A,
                const unsigned short* __restrict__ B,
                unsigned short* __restrict__ C)
{
    constexpr int K = D_REAL, N = D_HID;
    __shared__ __align__(16) unsigned short As[64 * 32];    // 4 KB
    __shared__ __align__(16) unsigned short Bs[128 * 32];   // 8 KB

    const int tid = threadIdx.x;
    const int rowBase = blockIdx.x * 64;
    const int colBase = blockIdx.y * 128;

    const int srow = tid >> 2;
    const int scol = (tid & 3) * 8;
    const unsigned short* gA = A + (size_t)(rowBase + srow) * K + scol;
    const unsigned short* gB = B + (size_t)(colBase + srow) * K + scol;
    // wave w stages A rows 16w..16w+15 = 1024 B -> base = w*512 shorts
    unsigned short* lA = As + (tid >> 6) * 512;
    unsigned short* lB = Bs + (tid >> 6) * 512;

    const int lane = tid & 63;
    const int wv   = tid >> 6;
    const int wm   = (wv >> 1) * 32;
    const int wn   = (wv & 1) * 64;
    const int frow = lane & 15;
    const int fk   = (lane >> 4) * 8;

    f32x4 acc[2][4];
    #pragma unroll
    for (int i = 0; i < 2; i++)
        #pragma unroll
        for (int j = 0; j < 4; j++) acc[i][j] = (f32x4)0.f;

    for (int k0 = 0; k0 < K; k0 += 32) {
        gload_lds16(gA,                lA);
        gload_lds16(gB,                lB);
        gload_lds16(gB + (size_t)64*K, lB + 2048);
        gA += 32; gB += 32;
        __syncthreads();

        bf16x8 af[2], bg[4];
        #pragma unroll
        for (int i = 0; i < 2; i++)
            af[i] = *reinterpret_cast<const bf16x8*>(&As[(wm + i*16 + frow) * 32 + fk]);
        #pragma unroll
        for (int j = 0; j < 4; j++)
            bg[j] = *reinterpret_cast<const bf16x8*>(&Bs[(wn + j*16 + frow) * 32 + fk]);

        #pragma unroll
        for (int i = 0; i < 2; i++)
            #pragma unroll
            for (int j = 0; j < 4; j++)
                acc[i][j] = __builtin_amdgcn_mfma_f32_16x16x32_bf16(af[i], bg[j], acc[i][j], 0, 0, 0);
        __syncthreads();
    }

    // Epilogue: bf16 scalar stores (C/D frag: row=(lane>>4)*4+r, col=lane&15)
    const int orow0 = wm + (lane >> 4) * 4;
    const int ocol0 = wn + frow;
    #pragma unroll
    for (int i = 0; i < 2; i++)
        #pragma unroll
        for (int r = 0; r < 4; r++) {
            unsigned short* dst = C + (size_t)(rowBase + orow0 + i*16 + r) * N + colBase + ocol0;
            #pragma unroll
            for (int j = 0; j < 4; j++)
                dst[j * 16] = f2bf(acc[i][j][r]);
        }
}

// ---------------------------------------------------------------------------
// GEMM2: out[M=8192][N=4096] = Hb * w2b^T + embed[ids], fp32 out.
// m97 K-loop (128x128, BK=32, 4 waves 2x2, 4x4 frags), scalar epilogue
// (round-2 form), 1-D grid with XCD-slab swizzle:
//   f&7 = XCD (HW round-robin heuristic); XCD k owns row tiles k*8..k*8+7
//   across all 32 col tiles -> per-XCD hot set ~1.3 MB (8 A-panels + B panel)
//   fits the 4 MB per-XCD L2, so K-loop operand re-reads become L2 hits.
// ---------------------------------------------------------------------------
__global__ __launch_bounds__(256)
void gemm2_mfma(const unsigned short* __restrict__ A,
                const unsigned short* __restrict__ B,
                const int* __restrict__ ids,
                const float* __restrict__ embed,
                float* __restrict__ C)
{
    constexpr int K = D_HID, N = D_MODEL;
    __shared__ __align__(16) unsigned short As[128 * 32];   // 8 KB
    __shared__ __align__(16) unsigned short Bs[128 * 32];   // 8 KB
    __shared__ int sIds[128];

    // bijective slab swizzle: f -> (rowTile, colTile)
    const int f   = blockIdx.x;          // 0..2047
    const int xcd = f & 7;
    const int idx = f >> 3;              // 0..255
    const int rowBase = (xcd * 8 + (idx & 7)) * 128;   // row tile 0..63
    const int colBase = (idx >> 3) * 128;              // col tile 0..31

    const int tid = threadIdx.x;
    if (tid < 128) sIds[tid] = ids[rowBase + tid];

    const int srow = tid >> 2;
    const int scol = (tid & 3) * 8;
    const unsigned short* gA = A + (size_t)(rowBase + srow) * K + scol;
    const unsigned short* gB = B + (size_t)(colBase + srow) * K + scol;
    unsigned short* lA = As + (tid >> 6) * 512;
    unsigned short* lB = Bs + (tid >> 6) * 512;

    const int lane = tid & 63;
    const int wv   = tid >> 6;
    const int wm   = (wv >> 1) * 64;
    const int wn   = (wv & 1) * 64;
    const int frow = lane & 15;
    const int fk   = (lane >> 4) * 8;

    f32x4 acc[4][4];
    #pragma unroll
    for (int i = 0; i < 4; i++)
        #pragma unroll
        for (int j = 0; j < 4; j++) acc[i][j] = (f32x4)0.f;

    for (int k0 = 0; k0 < K; k0 += 32) {
        gload_lds16(gA,                lA);
        gload_lds16(gA + (size_t)64*K, lA + 2048);
        gload_lds16(gB,                lB);
        gload_lds16(gB + (size_t)64*K, lB + 2048);
        gA += 32; gB += 32;
        __syncthreads();

        bf16x8 af[4], bg[4];
        #pragma unroll
        for (int i = 0; i < 4; i++)
            af[i] = *reinterpret_cast<const bf16x8*>(&As[(wm + i*16 + frow) * 32 + fk]);
        #pragma unroll
        for (int j = 0; j < 4; j++)
            bg[j] = *reinterpret_cast<const bf16x8*>(&Bs[(wn + j*16 + frow) * 32 + fk]);

        #pragma unroll
        for (int i = 0; i < 4; i++)
            #pragma unroll
            for (int j = 0; j < 4; j++)
                acc[i][j] = __builtin_amdgcn_mfma_f32_16x16x32_bf16(af[i], bg[j], acc[i][j], 0, 0, 0);
        __syncthreads();
    }

    // Scalar epilogue (round-2 form): C/D frag row=(lane>>4)*4+r, col=lane&15.
    const int orow0 = wm + (lane >> 4) * 4;
    const int ocol0 = wn + frow;
    #pragma unroll
    for (int i = 0; i < 4; i++) {
        #pragma unroll
        for (int r = 0; r < 4; r++) {
            const int lrow = orow0 + i * 16 + r;
            const size_t grow = (size_t)(rowBase + lrow);
            const float* e = embed + (size_t)sIds[lrow] * N + colBase + ocol0;
            #pragma unroll
            for (int j = 0; j < 4; j++)
                C[grow * N + colBase + ocol0 + j * 16] = acc[i][j][r] + e[j * 16];
        }
    }
}

// ---------------------------------------------------------------------------
// fp32 -> bf16 bulk convert of w1 and w2 in one launch
// ---------------------------------------------------------------------------
__global__ __launch_bounds__(256)
void convert2_bf16(const float* __restrict__ s1, unsigned short* __restrict__ d1, int n1,
                   const float* __restrict__ s2, unsigned short* __restrict__ d2, int n2)
{
    int i = blockIdx.x * 256 + threadIdx.x;
    const float* src; unsigned short* dst;
    if (i < n1) { src = s1; dst = d1; }
    else {
        i -= n1;
        if (i >= n2) return;
        src = s2; dst = d2;
    }
    const float4 v = reinterpret_cast<const float4*>(src)[i];
    ushort4 o;
    o.x = f2bf(v.x); o.y = f2bf(v.y); o.z = f2bf(v.z); o.w = f2bf(v.w);
    reinterpret_cast<ushort4*>(dst)[i] = o;
}

// ---------------------------------------------------------------------------
// Gather rows of real[ids[t]] -> bf16 Ag[t]. One block (192 thr) per token.
// ---------------------------------------------------------------------------
__global__ __launch_bounds__(192)
void gather_bf16(const float* __restrict__ real, const int* __restrict__ ids,
                 unsigned short* __restrict__ Ag)
{
    const int row = blockIdx.x;
    const int t = threadIdx.x;
    const float4 v = *reinterpret_cast<const float4*>(real + (size_t)ids[row] * D_REAL + t * 4);
    ushort4 o;
    o.x = f2bf(v.x); o.y = f2bf(v.y); o.z = f2bf(v.z); o.w = f2bf(v.w);
    *reinterpret_cast<ushort4*>(Ag + (size_t)row * D_REAL + t * 4) = o;
}

// ---------------------------------------------------------------------------
// In-place LayerNorm + ELU on bf16 H [TOKENS][512]. One wave per row.
// ---------------------------------------------------------------------------
__global__ __launch_bounds__(256)
void ln_elu_bf16(unsigned short* __restrict__ H,
                 const float* __restrict__ ln_w, const float* __restrict__ ln_b)
{
    const int row = blockIdx.x * 4 + (threadIdx.x >> 6);
    const int t = threadIdx.x & 63;
    unsigned short* x = H + (size_t)row * D_HID + t * 8;

    bf16x8 v = *reinterpret_cast<const bf16x8*>(x);
    float f[8], s = 0.f, ss = 0.f;
    #pragma unroll
    for (int j = 0; j < 8; j++) {
        f[j] = bf2f((unsigned short)v[j]);
        s += f[j]; ss += f[j] * f[j];
    }
    #pragma unroll
    for (int off = 32; off > 0; off >>= 1) {
        s  += __shfl_down(s, off);
        ss += __shfl_down(ss, off);
    }
    s = __shfl(s, 0); ss = __shfl(ss, 0);
    const float mu = s * (1.f / D_HID);
    const float var = ss * (1.f / D_HID) - mu * mu;
    const float rstd = rsqrtf(var + 1e-5f);

    const float4 w0 = *reinterpret_cast<const float4*>(ln_w + t * 8);
    const float4 w1 = *reinterpret_cast<const float4*>(ln_w + t * 8 + 4);
    const float4 b0 = *reinterpret_cast<const float4*>(ln_b + t * 8);
    const float4 b1 = *reinterpret_cast<const float4*>(ln_b + t * 8 + 4);
    const float wa[8] = { w0.x, w0.y, w0.z, w0.w, w1.x, w1.y, w1.z, w1.w };
    const float ba[8] = { b0.x, b0.y, b0.z, b0.w, b1.x, b1.y, b1.z, b1.w };

    bf16x8 o;
    #pragma unroll
    for (int j = 0; j < 8; j++) {
        float y = (f[j] - mu) * rstd * wa[j] + ba[j];
        y = y > 0.f ? y : expm1f(y);
        o[j] = (short)f2bf(y);
    }
    *reinterpret_cast<bf16x8*>(x) = o;
}

extern "C" void kernel_launch(void* const* d_in, const int* in_sizes, int n_in,
                              void* d_out, int out_size, void* d_ws, size_t ws_size,
                              hipStream_t stream)
{
    const float* real  = (const float*)d_in[0];   // [32000, 768]
    const float* embed = (const float*)d_in[1];   // [32000, 4096]
    const float* w1    = (const float*)d_in[2];   // [512, 768]
    const float* w2    = (const float*)d_in[3];   // [4096, 512]
    const float* ln_w  = (const float*)d_in[4];   // [512]
    const float* ln_b  = (const float*)d_in[5];   // [512]
    const int*   ids   = (const int*)d_in[6];     // [8192]
    float* out = (float*)d_out;                   // [8192, 4096] fp32

    unsigned short* Hb  = (unsigned short*)d_ws;             // [8192][512] bf16 (8 MB)
    unsigned short* w1b = Hb  + (size_t)TOKENS * D_HID;      // [512][768]  bf16
    unsigned short* w2b = w1b + (size_t)D_HID * D_REAL;      // [4096][512] bf16
    // d_out doubles as scratch for gathered bf16 A — fully overwritten by GEMM2.
    unsigned short* Ag  = (unsigned short*)d_out;            // [8192][768] bf16

    const int n1 = D_HID * D_REAL / 4, n2 = D_MODEL * D_HID / 4;
    convert2_bf16<<<(n1 + n2 + 255) / 256, 256, 0, stream>>>(w1, w1b, n1, w2, w2b, n2);
    gather_bf16<<<TOKENS, 192, 0, stream>>>(real, ids, Ag);

    dim3 g1(TOKENS / 64, D_HID / 128);
    gemm1_mfma<<<g1, 256, 0, stream>>>(Ag, w1b, Hb);

    ln_elu_bf16<<<TOKENS / 4, 256, 0, stream>>>(Hb, ln_w, ln_b);

    gemm2_mfma<<<2048, 256, 0, stream>>>(Hb, w2b, ids, embed, out);
}